// Round 1
// 49.475 us; speedup vs baseline: 1.3858x; 1.3858x over previous
//
#include <hip/hip_runtime.h>
#include <math.h>

// Radon forward, exact reference semantics (rotated-lattice bilinear gather).
//
// Round-7 changes vs round 6 (68.6 us total; tile2 64.2 us, VALUBusy 66%,
// Occupancy 40%, LDS conflicts 8.8M cyc):
//  * Staging rewritten around __builtin_amdgcn_global_load_lds (16B/lane):
//    canvases (260x262 f32x2, normal + transposed) carry a zero guard ring;
//    clamped per-lane SOURCE addresses land OOB taps in guaranteed-zero
//    guard cells, so staging has no per-cell bounds logic and no ds_write.
//    Tile rows are dense (TS2=84), so each bbox is one linear LDS region.
//  * bbox (r0,c0,rows,case,safe) precomputed per (t-pair,jb,ib) tuple in the
//    prep kernel -> main kernel reads one int4 + readfirstlane (SALU control)
//    instead of every thread redoing the 8-corner reduction each subtile.
//  * Gather inner loop: incremental U/V walk (dU=slope*STEP), fused float
//    address rel=(int)fma(fU,84,fV)+nbase, safety clamps removed (margins
//    re-derived: rows<=75<TROWS=76, cols<=79<TS2=84, +-1 slack for drift),
//    phantom-i masking only in the single tail subtile (uniform branch).
//  * i-split z: 2 -> 4 (grid 540x4 = 2160 blocks, better tail balance);
//    epilogue atomicAdd's straight into out (zeroed by prep) -> no part
//    buffer, no reduce kernel.
//  * Wave lane map: 32 j x 2 i per wave (spreads worst-angle bank pairs).

#define G       363
#define NT      180
#define PADB    53
#define STEP    (2.0f / 362.0f)
#define DEG2RAD 0.017453292519943295f

#define TS2     84          // tile row length (f32x2 cells), even (16B chunks row-pure)
#define TROWS   76          // max tile rows
#define NTILE   6400        // 50 chunks * 128 cells  (51,200 B LDS, 3 blocks/CU)
#define NJB     6
#define CW      262         // canvas cols
#define CH      260         // canvas rows  (image interior at [3..258]x[3..258])
#define NTUPLE  (90 * 6 * 12)

typedef __attribute__((ext_vector_type(2))) float f32x2;

#define GLOAD16(gp, lp) __builtin_amdgcn_global_load_lds(                     \
    (const __attribute__((address_space(1))) void*)(gp),                      \
    (__attribute__((address_space(3))) void*)(lp), 16, 0, 0)

// ---------------- fallback gather kernel (known-good, round 1) -------------
__global__ __launch_bounds__(256) void radon_fwd(
    const float* __restrict__ x, const int* __restrict__ theta,
    float* __restrict__ out)
{
    const int t = blockIdx.x / NJB, jb = blockIdx.x % NJB;
    const int jl = threadIdx.x, chunk = threadIdx.y;
    const int j = jb * 64 + jl;
    const float th = (float)theta[t] * DEG2RAD;
    const float c = cosf(th), s = sinf(th);
    const float xj = fmaf((float)j, STEP, -1.0f);
    const float s181 = s * 181.0f, c181 = c * 181.0f;
    const float bx = fmaf(c, xj, 1.0f) * 181.0f;
    const float by = fmaf(-s, xj, 1.0f) * 181.0f;
    const float* img0 = x;
    const float* img1 = x + 65536;
    float acc0 = 0.f, acc1 = 0.f;
    for (int i = chunk; i < G; i += 4) {
        const float xi = fmaf((float)i, STEP, -1.0f);
        const float ix = fmaf(s181, xi, bx);
        const float iy = fmaf(c181, xi, by);
        const float fx = floorf(ix), fy = floorf(iy);
        const int ix0 = (int)fx, iy0 = (int)fy;
        const float wx1 = ix - fx, wy1 = iy - fy;
        const float wx0 = 1.f - wx1, wy0 = 1.f - wy1;
        const int cc0 = ix0 - 53, cc1 = cc0 + 1, rr0 = iy0 - 53, rr1 = rr0 + 1;
        const float wxa = ((unsigned)cc0 < 256u) ? wx0 : 0.f;
        const float wxb = ((unsigned)cc1 < 256u) ? wx1 : 0.f;
        const float wya = ((unsigned)rr0 < 256u) ? wy0 : 0.f;
        const float wyb = ((unsigned)rr1 < 256u) ? wy1 : 0.f;
        const int c0c = min(max(cc0, 0), 255), c1c = min(max(cc1, 0), 255);
        const int r0b = min(max(rr0, 0), 255) << 8, r1b = min(max(rr1, 0), 255) << 8;
        const float w00 = wya * wxa, w01 = wya * wxb, w10 = wyb * wxa, w11 = wyb * wxb;
        acc0 = fmaf(img0[r0b + c0c], w00, acc0);
        acc0 = fmaf(img0[r0b + c1c], w01, acc0);
        acc0 = fmaf(img0[r1b + c0c], w10, acc0);
        acc0 = fmaf(img0[r1b + c1c], w11, acc0);
        acc1 = fmaf(img1[r0b + c0c], w00, acc1);
        acc1 = fmaf(img1[r0b + c1c], w01, acc1);
        acc1 = fmaf(img1[r1b + c0c], w10, acc1);
        acc1 = fmaf(img1[r1b + c1c], w11, acc1);
    }
    __shared__ float red[2][4][64];
    red[0][chunk][jl] = acc0;
    red[1][chunk][jl] = acc1;
    __syncthreads();
    if (threadIdx.y < 2 && j < G) {
        const int n = threadIdx.y;
        out[n * (G * NT) + j * NT + t] =
            red[n][0][jl] + red[n][1][jl] + red[n][2][jl] + red[n][3][jl];
    }
}

// ------------- prep: canvases + bbox table + zero(out) ---------------------
// Block roles by blockIdx.x:
//   [0,81)    : interleave image into guarded canvases xIc (row-major) and
//               xTIc (transposed), zero guard ring.
//   [81,107)  : bbox table, one tuple (tg,jb,ib) per thread.
//   [107,235) : zero out (32670 float4).
__global__ __launch_bounds__(256) void prep_k(
    const float* __restrict__ x, const int* __restrict__ theta,
    f32x2* __restrict__ xIc, f32x2* __restrict__ xTIc,
    int4* __restrict__ bbox, float* __restrict__ out)
{
    const int bid = blockIdx.x;
    const int tx = threadIdx.x, ty = threadIdx.y;
    const int tid = ty * 32 + tx;

    if (bid < 81) {
        __shared__ f32x2 tl[32][33];
        const int cx0 = (bid % 9) * 32, cy0 = (bid / 9) * 32;
        #pragma unroll
        for (int dy = 0; dy < 32; dy += 8) {
            const int cy = cy0 + ty + dy, cx = cx0 + tx;
            const int pr = cy - 3, pc = cx - 3;
            f32x2 v = {0.0f, 0.0f};
            if ((unsigned)pr < 256u && (unsigned)pc < 256u) {
                const int p = pr * 256 + pc;
                v.x = x[p]; v.y = x[p + 65536];
            }
            if (cy < CH && cx < CW) xIc[cy * CW + cx] = v;
            tl[ty + dy][tx] = v;
        }
        __syncthreads();
        #pragma unroll
        for (int dy = 0; dy < 32; dy += 8) {
            const int rp = cx0 + ty + dy, cp = cy0 + tx;
            if (rp < CH && cp < CW) xTIc[rp * CW + cp] = tl[tx][ty + dy];
        }
    } else if (bid < 107) {
        const int tuple = (bid - 81) * 256 + tid;
        if (tuple < NTUPLE) {
            const int tg  = tuple / 72, rem = tuple - tg * 72;
            const int jb  = rem / 12,   ib  = rem - jb * 12;
            const float thA = (float)theta[tg * 2]     * DEG2RAD;
            const float thB = (float)theta[tg * 2 + 1] * DEG2RAD;
            const float cA = cosf(thA), sA = sinf(thA);
            const float cB = cosf(thB), sB = sinf(thB);
            const float xjm = fmaf((float)(jb * 64),      STEP, -1.0f);
            const float xjM = fmaf((float)(jb * 64 + 63), STEP, -1.0f);
            const float xim = fmaf((float)(ib * 32),      STEP, -1.0f);
            const float xiM = fmaf((float)(ib * 32 + 31), STEP, -1.0f);
            float ixmin = 1e30f, ixmax = -1e30f, iymin = 1e30f, iymax = -1e30f;
            #pragma unroll
            for (int qq = 0; qq < 8; ++qq) {
                const float cc  = (qq & 4) ? cB : cA;
                const float ss  = (qq & 4) ? sB : sA;
                const float xjc = (qq & 1) ? xjM : xjm;
                const float xic = (qq & 2) ? xiM : xim;
                const float bxq = fmaf(cc,  xjc, 1.0f) * 181.0f;
                const float byq = fmaf(-ss, xjc, 1.0f) * 181.0f;
                const float ixq = fmaf(ss * 181.0f, xic, bxq);
                const float iyq = fmaf(cc * 181.0f, xic, byq);
                ixmin = fminf(ixmin, ixq); ixmax = fmaxf(ixmax, ixq);
                iymin = fminf(iymin, iyq); iymax = fmaxf(iymax, iyq);
            }
            const int caseA = (fabsf(cA) + fabsf(cB) >= fabsf(sA) + fabsf(sB));
            const float Umin = caseA ? iymin : ixmin;
            const float Umax = caseA ? iymax : ixmax;
            const float Vmin = caseA ? ixmin : iymin;
            const int r0 = (int)floorf(Umin) - 1;
            const int c0 = (int)floorf(Vmin) - 1;
            int rows = (int)floorf(Umax) - (int)floorf(Umin) + 4;
            rows = min(rows, TROWS);
            const int nchunk = (rows * TS2 + 127) >> 7;     // <= 50
            const int r0p = r0 - PADB, c0p = c0 - PADB;
            const int tyLast = (nchunk * 128 - 1) / TS2;
            const int safe = (r0p >= -3) && (r0p + tyLast <= 256)
                          && (c0p >= -3) && (c0p + 83 <= 257);
            bbox[tuple] = make_int4(r0p, c0p,
                                    nchunk | (safe << 8) | (caseA << 9),
                                    -(r0 * TS2 + c0));
        }
    } else {
        const int idx = (bid - 107) * 256 + tid;            // out: 130680 f32
        if (idx < 32670) ((float4*)out)[idx] = make_float4(0.f, 0.f, 0.f, 0.f);
    }
}

// ---------------- gather inner loop (8 i-steps) ----------------------------
template<bool TAIL>
__device__ __forceinline__ void gather8(const f32x2* __restrict__ tl,
    float Uf, float Vf, float dU, float dV, int nbase, int iexc,
    f32x2& acc0, f32x2& acc1)
{
    #pragma unroll
    for (int k = 0; k < 8; ++k) {
        const float fU = floorf(Uf), fV = floorf(Vf);
        float wU1 = Uf - fU;
        const float wV1 = Vf - fV;
        float wU0 = 1.0f - wU1;
        const float wV0 = 1.0f - wV1;
        // fU*84+fV exact (integers < 2^24); rel = ty*84+tx in [0, 6384)
        const int rel = (int)fmaf(fU, (float)TS2, fV) + nbase;
        const f32x2 t00 = tl[rel];
        const f32x2 t01 = tl[rel + 1];
        const f32x2 t10 = tl[rel + TS2];
        const f32x2 t11 = tl[rel + TS2 + 1];
        if (TAIL && k >= iexc) { wU0 = 0.0f; wU1 = 0.0f; }   // phantom i >= G
        f32x2 r0v = t00 * (f32x2){wV0, wV0};
        r0v = __builtin_elementwise_fma(t01, (f32x2){wV1, wV1}, r0v);
        f32x2 r1v = t10 * (f32x2){wV0, wV0};
        r1v = __builtin_elementwise_fma(t11, (f32x2){wV1, wV1}, r1v);
        acc0 = __builtin_elementwise_fma(r0v, (f32x2){wU0, wU0}, acc0);
        acc1 = __builtin_elementwise_fma(r1v, (f32x2){wU1, wU1}, acc1);
        Uf += dU; Vf += dV;
    }
}

// ---------------- main tiled gather ----------------------------------------
__global__ __launch_bounds__(512) void radon_tile3(
    const f32x2* __restrict__ xIc, const f32x2* __restrict__ xTIc,
    const int*   __restrict__ theta, const int4* __restrict__ bbox,
    float* __restrict__ out)
{
    __shared__ f32x2 tile[NTILE];          // 51,200 B -> 3 blocks/CU

    const int blk  = blockIdx.x;           // 0..539
    const int z    = blockIdx.y;           // 0..3, handles ib = 3z..3z+2
    const int tg   = blk / 6;
    const int jb   = blk - tg * 6;
    const int tid  = threadIdx.x;
    const int lane = tid & 63;
    const int wid  = tid >> 6;
    const int a    = wid >> 2;             // angle of pair
    const int jh   = (wid >> 1) & 1;       // j half (32)
    const int qq   = wid & 1;              // i 16-group
    const int jl   = lane & 31;
    const int kk   = lane >> 5;            // i 8-subgroup within wave

    const int t = tg * 2 + a;
    const float th = (float)theta[t] * DEG2RAD;
    const float c = cosf(th), s = sinf(th);
    const float s181 = s * 181.0f, c181 = c * 181.0f;

    const int   j  = jb * 64 + jh * 32 + jl;   // phantom j >= 363 ok
    const float xj = fmaf((float)j, STEP, -1.0f);
    const float bx = fmaf(c,  xj, 1.0f) * 181.0f;
    const float by = fmaf(-s, xj, 1.0f) * 181.0f;

    const int lane2 = lane * 2;
    const float fiofs = (float)(qq * 16 + kk * 8);

    f32x2 acc0 = {0.0f, 0.0f}, acc1 = {0.0f, 0.0f};

    const int ib0 = z * 3;
    for (int ibi = 0; ibi < 3; ++ibi) {
        const int ib = ib0 + ibi;
        const int4 bb = bbox[(tg * 6 + jb) * 12 + ib];
        const int r0p    = __builtin_amdgcn_readfirstlane(bb.x);
        const int c0p    = __builtin_amdgcn_readfirstlane(bb.y);
        const int flags  = __builtin_amdgcn_readfirstlane(bb.z);
        const int nbase  = __builtin_amdgcn_readfirstlane(bb.w);
        const int nchunk = flags & 255;
        const int safe   = (flags >> 8) & 1;
        const int caseA  = (flags >> 9) & 1;

        const f32x2* __restrict__ srcC = caseA ? xIc : xTIc;

        __syncthreads();                   // previous tile fully consumed

        // ---- stage bbox: 16B/lane global_load_lds, linear LDS dest ----
        if (safe) {
            const int B = (r0p + 3) * CW + (c0p + 3);
            for (int h = wid; h < nchunk; h += 8) {
                const int hs   = __builtin_amdgcn_readfirstlane(h);
                const int cell = (hs << 7) + lane2;
                const int tyc  = cell / TS2;
                const int txc  = cell - tyc * TS2;
                const f32x2* gp = srcC + (tyc * CW + txc + B);
                GLOAD16(gp, (char*)tile + (hs << 10));
            }
        } else {
            // clamp into guard ring: OOB taps read guaranteed zeros
            for (int h = wid; h < nchunk; h += 8) {
                const int hs   = __builtin_amdgcn_readfirstlane(h);
                const int cell = (hs << 7) + lane2;
                const int tyc  = cell / TS2;
                const int txc  = cell - tyc * TS2;
                const int rc = min(max(r0p + tyc, -3), 256) + 3;
                const int cc = min(max(c0p + txc, -3), 257) + 3;
                const f32x2* gp = srcC + (rc * CW + cc);
                GLOAD16(gp, (char*)tile + (hs << 10));
            }
        }
        __syncthreads();

        // ---- gather: 8 samples/lane, incremental U/V walk ----
        const int i0 = ib * 32;
        const float slopeU = caseA ? c181 : s181;
        const float slopeV = caseA ? s181 : c181;
        const float dU = slopeU * STEP;    // ~= +-cos/sin per i-step
        const float dV = slopeV * STEP;
        const float U00 = (caseA ? by : bx) - slopeU;
        const float V00 = (caseA ? bx : by) - slopeV;
        const float fi = (float)i0 + fiofs;
        const float Uf = fmaf(dU, fi, U00);
        const float Vf = fmaf(dV, fi, V00);
        const int ibase = i0 + qq * 16 + kk * 8;

        if (i0 + qq * 16 + 15 < G) {       // wave-uniform (qq per-wave)
            gather8<false>(tile, Uf, Vf, dU, dV, nbase, 8, acc0, acc1);
        } else {
            gather8<true>(tile, Uf, Vf, dU, dV, nbase, G - ibase, acc0, acc1);
        }
    }

    // ---- reduce (qq waves x kk lanes) and atomically add into out ----
    __syncthreads();
    f32x2* red = tile;
    red[wid * 64 + lane] = acc0 + acc1;
    __syncthreads();

    if (tid < 128) {
        const int aa = tid >> 6, jj = tid & 63;
        const int jhh = jj >> 5, jll = jj & 31;
        const int w0 = aa * 4 + jhh * 2;
        f32x2 v = red[w0 * 64 + jll];
        v += red[w0 * 64 + jll + 32];
        v += red[(w0 + 1) * 64 + jll];
        v += red[(w0 + 1) * 64 + jll + 32];
        const int jo = jb * 64 + jj;
        if (jo < G) {
            const int tt = tg * 2 + aa;
            atomicAdd(&out[jo * NT + tt],          v.x);   // n = 0
            atomicAdd(&out[G * NT + jo * NT + tt], v.y);   // n = 1
        }
    }
}

extern "C" void kernel_launch(void* const* d_in, const int* in_sizes, int n_in,
                              void* d_out, int out_size, void* d_ws, size_t ws_size,
                              hipStream_t stream) {
    const float* x     = (const float*)d_in[0];
    const int*   theta = (const int*)d_in[1];
    float*       out   = (float*)d_out;

    const size_t XIC_OFF  = 0;
    const size_t XTIC_OFF = (size_t)CH * CW * 8;                 // 544,960
    const size_t BBOX_OFF = 2 * XTIC_OFF;                        // 1,089,920
    const size_t NEED     = BBOX_OFF + (size_t)NTUPLE * 16;      // ~1.19 MiB

    if (ws_size < NEED) {   // fallback: known-good gather kernel
        hipLaunchKernelGGL(radon_fwd, dim3(NT * NJB), dim3(64, 4), 0, stream,
                           x, theta, out);
        return;
    }

    f32x2* xIc  = (f32x2*)((char*)d_ws + XIC_OFF);
    f32x2* xTIc = (f32x2*)((char*)d_ws + XTIC_OFF);
    int4*  bbox = (int4*)((char*)d_ws + BBOX_OFF);

    hipLaunchKernelGGL(prep_k, dim3(235), dim3(32, 8), 0, stream,
                       x, theta, xIc, xTIc, bbox, out);
    hipLaunchKernelGGL(radon_tile3, dim3(540, 4), dim3(512), 0, stream,
                       xIc, xTIc, theta, bbox, out);
}